// Round 3
// baseline (273.285 us; speedup 1.0000x reference)
//
#include <hip/hip_runtime.h>

// TPLoss: pred [B,N] fp32, labels [B,N] int32 (0/1) -> scalar fp32
//   s = sigmoid(pred); TP = sum(s*l); SP = sum(s); SL = sum(l)
//   denom = 1 - N + SP + SL - 2*TP ;  loss = -mean_b(TP/denom)
//
// R2 lesson: compiler (VGPR=32) sank preloads back into the loop -> one
// vmcnt(0) per iteration -> latency-bound at 2.6 TB/s effective.
// R3: wave-per-row + batched loads fenced with sched_barrier(0) so 16
// dwordx4 stay in flight per wave, and raw v_exp/v_rcp sigmoid to kill
// the ~35-cycle IEEE divide chain per element.

#define BDIM 256
#define WPB (BDIM / 64)          // waves per block = 4 (one row each)
#define ROWS 4096
#define COLS 8192
#define VPL (COLS / 64 / 4)      // float4 per lane per row = 32
#define BATCH 8
#define NBATCH (VPL / BATCH)     // 4 batches

__global__ __launch_bounds__(BDIM, 4) void tploss_rows(
    const float* __restrict__ pred,
    const int* __restrict__ labels,
    float* __restrict__ row_out)
{
    const int lane = threadIdx.x & 63;
    const int row  = blockIdx.x * WPB + (threadIdx.x >> 6);

    const float4* p4 = (const float4*)(pred   + (size_t)row * COLS) + lane;
    const int4*   l4 = (const int4*)  (labels + (size_t)row * COLS) + lane;

    float sp = 0.0f;   // sum sigmoid
    float tp = 0.0f;   // sum sigmoid*label
    int   sl = 0;      // sum label (exact)

    for (int b = 0; b < NBATCH; ++b) {
        float4 pv[BATCH];
        int4   lv[BATCH];
#pragma unroll
        for (int i = 0; i < BATCH; ++i) pv[i] = p4[(b * BATCH + i) * 64];
#pragma unroll
        for (int i = 0; i < BATCH; ++i) lv[i] = l4[(b * BATCH + i) * 64];

        // Hard scheduling fence: none of the compute below may be hoisted
        // above, none of the 16 loads above may sink below. All 16 issue
        // back-to-back -> 16 KB in flight per wave.
        __builtin_amdgcn_sched_barrier(0);

#pragma unroll
        for (int i = 0; i < BATCH; ++i) {
            // sigmoid via raw v_exp + v_rcp (~2^-21 rel err, well inside
            // the 1e-2 threshold; rcp(inf)=0 gives the correct x->-inf limit)
            float e0 = __expf(-pv[i].x);
            float e1 = __expf(-pv[i].y);
            float e2 = __expf(-pv[i].z);
            float e3 = __expf(-pv[i].w);
            float s0 = __builtin_amdgcn_rcpf(1.0f + e0);
            float s1 = __builtin_amdgcn_rcpf(1.0f + e1);
            float s2 = __builtin_amdgcn_rcpf(1.0f + e2);
            float s3 = __builtin_amdgcn_rcpf(1.0f + e3);

            sp += (s0 + s1) + (s2 + s3);
            tp = fmaf(s0, (float)lv[i].x, tp);
            tp = fmaf(s1, (float)lv[i].y, tp);
            tp = fmaf(s2, (float)lv[i].z, tp);
            tp = fmaf(s3, (float)lv[i].w, tp);
            sl += (lv[i].x + lv[i].y) + (lv[i].z + lv[i].w);
        }
    }

    float slf = (float)sl;

    // wave-64 butterfly; no LDS, no __syncthreads
#pragma unroll
    for (int off = 32; off > 0; off >>= 1) {
        sp  += __shfl_down(sp,  off, 64);
        tp  += __shfl_down(tp,  off, 64);
        slf += __shfl_down(slf, off, 64);
    }

    if (lane == 0) {
        float denom = 1.0f - (float)COLS + sp + slf - 2.0f * tp;
        row_out[row] = tp / denom;   // one plain store per row, no atomics
    }
}

__global__ __launch_bounds__(BDIM) void tploss_reduce(
    const float* __restrict__ row_out,
    float* __restrict__ out)
{
    const int tid = threadIdx.x;
    float s = 0.0f;
#pragma unroll
    for (int i = 0; i < ROWS / BDIM; ++i)
        s += row_out[i * BDIM + tid];

#pragma unroll
    for (int off = 32; off > 0; off >>= 1)
        s += __shfl_down(s, off, 64);

    __shared__ float sw[BDIM / 64];
    const int wave = tid >> 6;
    const int lane = tid & 63;
    if (lane == 0) sw[wave] = s;
    __syncthreads();

    if (tid == 0) {
        float tot = (sw[0] + sw[1]) + (sw[2] + sw[3]);
        out[0] = -tot * (1.0f / (float)ROWS);
    }
}

extern "C" void kernel_launch(void* const* d_in, const int* in_sizes, int n_in,
                              void* d_out, int out_size, void* d_ws, size_t ws_size,
                              hipStream_t stream) {
    const float* pred   = (const float*)d_in[0];
    const int*   labels = (const int*)d_in[1];
    float* row_out = (float*)d_ws;   // 4096 floats; fully overwritten each call

    tploss_rows<<<ROWS / WPB, BDIM, 0, stream>>>(pred, labels, row_out);
    tploss_reduce<<<1, BDIM, 0, stream>>>(row_out, (float*)d_out);
}